// Round 7
// baseline (370.159 us; speedup 1.0000x reference)
//
#include <hip/hip_runtime.h>
#include <hip/hip_bf16.h>

// GCNConv: out = D^-1/2 (A+I) D^-1/2 (X W) + b
// N=100000, E=1600000, IN=128, OUT=64. edge_index int32, [row(E) | col(E)].
//
// Pipeline v5 — 6 kernels, bf16 hp:
//   1. count:       per-block LDS histogram over 782 buckets -> blkcnt[bucket][block]
//   2. scan_fused:  single-block scan of blkcnt -> blkoff + bucket_start
//   3. place:       pairs[pos] = row | lcol<<17 (LDS cursors, no global atomics)
//   4. bucket_sort: in-LDS counting sort per bucket -> csr_row (coalesced),
//                   row_start, dinv   (replaces bdeg + 3 scans + fill)
//   5. gemm:        hp_bf16 = (x @ W) * dinv[row]   (overlays pairs)
//   6. aggregate:   wave per node, 8-deep bf16 gather unroll

#define IN_CH 128
#define OUT_CH 64
#define BSHIFT 7            // 128 nodes per bucket
#define BNODES 128
#define MAX_NB 800
#define CH_EDGES 16384      // edges per partition block
#define SORT_CAP 4096       // LDS sort capacity (avg bucket = 2046 edges)

__device__ __forceinline__ float b2f(unsigned short u) {
    union { unsigned int i; float f; } v; v.i = (unsigned int)u << 16; return v.f;
}
__device__ __forceinline__ unsigned short f2b(float f) {   // RNE
    unsigned int u = __float_as_uint(f);
    return (unsigned short)((u + 0x7FFFu + ((u >> 16) & 1u)) >> 16);
}

// ---------------- 1: per-block bucket histogram ----------------
__global__ __launch_bounds__(256) void count_kernel(const int* __restrict__ col,
                                                    int* __restrict__ blkcnt,
                                                    int E, int NBLK, int NB) {
    __shared__ int h[MAX_NB];
    int tid = threadIdx.x;
    for (int i = tid; i < NB; i += 256) h[i] = 0;
    __syncthreads();
    int e0 = blockIdx.x * CH_EDGES;
    #pragma unroll 4
    for (int r = 0; r < CH_EDGES / 256; ++r) {
        int e = e0 + r * 256 + tid;
        if (e < E) atomicAdd(&h[col[e] >> BSHIFT], 1);
    }
    __syncthreads();
    for (int i = tid; i < NB; i += 256) blkcnt[i * NBLK + blockIdx.x] = h[i];
}

// ---------------- 2: single-block fused scan ----------------
// blkoff = exclusive scan of blkcnt (bucket-major); bucket_start[b]=blkoff[b*NBLK]
__global__ __launch_bounds__(1024) void scan_fused_kernel(const int* __restrict__ blkcnt,
                                                          int* __restrict__ blkoff,
                                                          int* __restrict__ bucket_start,
                                                          int TOT, int NBLK, int NB, int E) {
    __shared__ int s[1024];
    int tid   = threadIdx.x;
    int chunk = (TOT + 1023) / 1024;
    int lo = tid * chunk, hi = min(lo + chunk, TOT);
    int sum = 0;
    for (int i = lo; i < hi; ++i) sum += blkcnt[i];
    s[tid] = sum; __syncthreads();
    #pragma unroll
    for (int off = 1; off < 1024; off <<= 1) {
        int t = (tid >= off) ? s[tid - off] : 0;
        __syncthreads();
        s[tid] += t;
        __syncthreads();
    }
    int run = s[tid] - sum;          // exclusive prefix of this chunk
    for (int i = lo; i < hi; ++i) { int v = blkcnt[i]; blkoff[i] = run; run += v; }
    __syncthreads();                 // make blkoff visible block-wide
    for (int i = tid; i < NB; i += 1024) bucket_start[i] = blkoff[i * NBLK];
    if (tid == 0) bucket_start[NB] = E;
}

// ---------------- 3: place into pairs (no global atomics) ----------------
__global__ __launch_bounds__(256) void place_kernel(const int* __restrict__ row,
                                                    const int* __restrict__ col,
                                                    const int* __restrict__ blkoff,
                                                    int* __restrict__ pairs,
                                                    int E, int NBLK, int NB) {
    __shared__ int cur[MAX_NB];
    int tid = threadIdx.x;
    for (int i = tid; i < NB; i += 256) cur[i] = blkoff[i * NBLK + blockIdx.x];
    __syncthreads();
    int e0 = blockIdx.x * CH_EDGES;
    #pragma unroll 4
    for (int r2 = 0; r2 < CH_EDGES / 256; ++r2) {
        int e = e0 + r2 * 256 + tid;
        if (e < E) {
            int c = col[e];
            int b = c >> BSHIFT;
            int pos = atomicAdd(&cur[b], 1);          // LDS atomic
            pairs[pos] = row[e] | ((c & (BNODES - 1)) << 17);   // n < 2^17
        }
    }
}

// ---------------- 4: per-bucket in-LDS counting sort ----------------
// Emits: csr_row (node-sorted, coalesced writes), row_start, dinv.
__global__ __launch_bounds__(256) void bucket_sort_kernel(
    const int* __restrict__ bucket_start, const int* __restrict__ pairs,
    int* __restrict__ csr_row, int* __restrict__ row_start,
    float* __restrict__ dinv, int n, int E)
{
    __shared__ int cnt[BNODES];      // counts -> inclusive scan
    __shared__ int deg[BNODES];
    __shared__ int cur[BNODES];
    __shared__ int sorted[SORT_CAP];

    int b = blockIdx.x, tid = threadIdx.x;
    int node0 = b << BSHIFT;
    int nodeCnt = min(BNODES, n - node0);
    int s0 = bucket_start[b], s1 = bucket_start[b + 1];
    int m = s1 - s0;

    if (tid < BNODES) cnt[tid] = 0;
    __syncthreads();
    for (int e = s0 + tid; e < s1; e += 256) atomicAdd(&cnt[pairs[e] >> 17], 1);
    __syncthreads();
    if (tid < BNODES) deg[tid] = cnt[tid];
    __syncthreads();
    #pragma unroll
    for (int off = 1; off < BNODES; off <<= 1) {      // inclusive scan over 128
        int t = (tid >= off && tid < BNODES) ? cnt[tid - off] : 0;
        __syncthreads();
        if (tid < BNODES) cnt[tid] += t;
        __syncthreads();
    }
    if (tid < BNODES) {
        int excl = cnt[tid] - deg[tid];
        cur[tid] = excl;
        if (tid < nodeCnt) {
            row_start[node0 + tid] = s0 + excl;
            dinv[node0 + tid] = rsqrtf((float)(deg[tid] + 1));   // +1 self loop
        }
    }
    if (b == gridDim.x - 1 && tid == 0) row_start[n] = E;
    __syncthreads();

    if (m <= SORT_CAP) {
        for (int e = s0 + tid; e < s1; e += 256) {
            int p   = pairs[e];
            int pos = atomicAdd(&cur[p >> 17], 1);
            sorted[pos] = p & 0x1FFFF;
        }
        __syncthreads();
        for (int i = tid; i < m; i += 256) csr_row[s0 + i] = sorted[i];
    } else {   // fallback: direct global scatter (statistically unreachable)
        if (tid < BNODES) cur[tid] += s0;
        __syncthreads();
        for (int e = s0 + tid; e < s1; e += 256) {
            int p   = pairs[e];
            int pos = atomicAdd(&cur[p >> 17], 1);
            csr_row[pos] = p & 0x1FFFF;
        }
    }
}

// ---------------- 5: GEMM hp_bf16 = (x @ W) * dinv[row] ----------------
__device__ __forceinline__ void fma4(float4& a, float s, const float4& v) {
    a.x = fmaf(s, v.x, a.x);
    a.y = fmaf(s, v.y, a.y);
    a.z = fmaf(s, v.z, a.z);
    a.w = fmaf(s, v.w, a.w);
}

__global__ __launch_bounds__(256) void gemm_kernel(
    const float* __restrict__ x, const float* __restrict__ W,
    const float* __restrict__ dinv, unsigned short* __restrict__ hpb, int n)
{
    __shared__ float xl[64 * 128];   // 32 KB, XOR-swizzled float4 chunks
    __shared__ float wl[128 * 64];   // 32 KB, linear k*64+c

    int tid  = threadIdx.x;
    int row0 = blockIdx.x * 64;

    {
        const float4* wg = (const float4*)W;
        float4* wls = (float4*)wl;
        #pragma unroll
        for (int i = 0; i < 8; ++i) wls[tid + i * 256] = wg[tid + i * 256];
    }
    {
        float4* xls = (float4*)xl;
        #pragma unroll
        for (int i = 0; i < 8; ++i) {
            int f  = tid + i * 256;
            int r  = f >> 5;
            int c0 = f & 31;
            int gr = row0 + r;
            float4 v = make_float4(0.f, 0.f, 0.f, 0.f);
            if (gr < n) v = ((const float4*)(x + (size_t)gr * IN_CH))[c0];
            xls[(r << 5) | (c0 ^ (r & 7))] = v;
        }
    }
    __syncthreads();

    int tr = tid & 15;
    int tc = tid >> 4;

    float4 acc0 = {0,0,0,0}, acc1 = {0,0,0,0}, acc2 = {0,0,0,0}, acc3 = {0,0,0,0};
    const float4* xl4 = (const float4*)xl;
    const float4* wl4 = (const float4*)wl;

    #pragma unroll 4
    for (int k4 = 0; k4 < 32; ++k4) {
        int sc = k4 ^ (tr & 7);
        float4 xa0 = xl4[((tr     ) << 5) | sc];
        float4 xa1 = xl4[((tr + 16) << 5) | sc];
        float4 xa2 = xl4[((tr + 32) << 5) | sc];
        float4 xa3 = xl4[((tr + 48) << 5) | sc];
        float4 wb0 = wl4[((k4 * 4 + 0) << 4) | tc];
        float4 wb1 = wl4[((k4 * 4 + 1) << 4) | tc];
        float4 wb2 = wl4[((k4 * 4 + 2) << 4) | tc];
        float4 wb3 = wl4[((k4 * 4 + 3) << 4) | tc];

        fma4(acc0, xa0.x, wb0); fma4(acc0, xa0.y, wb1); fma4(acc0, xa0.z, wb2); fma4(acc0, xa0.w, wb3);
        fma4(acc1, xa1.x, wb0); fma4(acc1, xa1.y, wb1); fma4(acc1, xa1.z, wb2); fma4(acc1, xa1.w, wb3);
        fma4(acc2, xa2.x, wb0); fma4(acc2, xa2.y, wb1); fma4(acc2, xa2.z, wb2); fma4(acc2, xa2.w, wb3);
        fma4(acc3, xa3.x, wb0); fma4(acc3, xa3.y, wb1); fma4(acc3, xa3.z, wb2); fma4(acc3, xa3.w, wb3);
    }

    float4 accs[4] = {acc0, acc1, acc2, acc3};
    #pragma unroll
    for (int i = 0; i < 4; ++i) {
        int gr = row0 + tr + 16 * i;
        if (gr < n) {
            float di = dinv[gr];
            float4 a = accs[i];
            ushort4 h4;
            h4.x = f2b(a.x * di); h4.y = f2b(a.y * di);
            h4.z = f2b(a.z * di); h4.w = f2b(a.w * di);
            ((ushort4*)(hpb + (size_t)gr * OUT_CH))[tc] = h4;
        }
    }
}

// ---------------- 6: aggregate, bf16 gathers --------------------------------
__global__ __launch_bounds__(256) void aggregate_kernel(
    const int* __restrict__ row_start, const int* __restrict__ csr_row,
    const unsigned short* __restrict__ hpb, const float* __restrict__ dinv,
    const float* __restrict__ bias, float* __restrict__ out, int n)
{
    int wid  = (blockIdx.x * 256 + threadIdx.x) >> 6;   // node id
    int lane = threadIdx.x & 63;
    if (wid >= n) return;

    int s0 = row_start[wid];
    int s1 = row_start[wid + 1];

    float self = b2f(hpb[(size_t)wid * OUT_CH + lane]);
    float a0 = 0.f, a1 = 0.f, a2 = 0.f, a3 = 0.f;
    float a4 = 0.f, a5 = 0.f, a6 = 0.f, a7 = 0.f;

    for (int base = s0; base < s1; base += 64) {
        int cnt  = min(64, s1 - base);
        int ridx = (base + lane < s1) ? csr_row[base + lane] : 0;
        int j = 0;
        for (; j + 8 <= cnt; j += 8) {
            int r0 = __shfl(ridx, j);
            int r1 = __shfl(ridx, j + 1);
            int r2 = __shfl(ridx, j + 2);
            int r3 = __shfl(ridx, j + 3);
            int r4 = __shfl(ridx, j + 4);
            int r5 = __shfl(ridx, j + 5);
            int r6 = __shfl(ridx, j + 6);
            int r7 = __shfl(ridx, j + 7);
            a0 += b2f(hpb[(size_t)r0 * OUT_CH + lane]);
            a1 += b2f(hpb[(size_t)r1 * OUT_CH + lane]);
            a2 += b2f(hpb[(size_t)r2 * OUT_CH + lane]);
            a3 += b2f(hpb[(size_t)r3 * OUT_CH + lane]);
            a4 += b2f(hpb[(size_t)r4 * OUT_CH + lane]);
            a5 += b2f(hpb[(size_t)r5 * OUT_CH + lane]);
            a6 += b2f(hpb[(size_t)r6 * OUT_CH + lane]);
            a7 += b2f(hpb[(size_t)r7 * OUT_CH + lane]);
        }
        for (; j < cnt; ++j) {
            int r = __shfl(ridx, j);
            a0 += b2f(hpb[(size_t)r * OUT_CH + lane]);
        }
    }
    float acc = self + (((a0 + a1) + (a2 + a3)) + ((a4 + a5) + (a6 + a7)));
    out[(size_t)wid * OUT_CH + lane] = fmaf(dinv[wid], acc, bias[lane]);
}

extern "C" void kernel_launch(void* const* d_in, const int* in_sizes, int n_in,
                              void* d_out, int out_size, void* d_ws, size_t ws_size,
                              hipStream_t stream) {
    const float* x  = (const float*)d_in[0];
    const int*   ei = (const int*)d_in[1];
    const float* W  = (const float*)d_in[2];
    const float* b  = (const float*)d_in[3];
    float*       out = (float*)d_out;

    int n = in_sizes[0] / IN_CH;     // 100000
    int E = in_sizes[1] / 2;         // 1600000
    const int* row = ei;
    const int* col = ei + E;

    int NB   = (n + BNODES - 1) >> BSHIFT;           // 782
    int NBLK = (E + CH_EDGES - 1) / CH_EDGES;        // 98
    int TOT  = NB * NBLK;                            // 76636 (<= 1024*chunk)

    // workspace layout; hpb (bf16, n*64) overlays pairs (dead after bucket_sort)
    char* ws = (char*)d_ws;
    int*   blkcnt       = (int*)ws;   ws += (size_t)TOT * 4;
    int*   blkoff       = (int*)ws;   ws += (size_t)TOT * 4;
    int*   bucket_start = (int*)ws;   ws += (size_t)(NB + 1) * 4;
    int*   row_start    = (int*)ws;   ws += (size_t)(n + 1) * 4;
    float* dinv         = (float*)ws; ws += (size_t)n * 4;
    int*   csr_row      = (int*)ws;   ws += (size_t)E * 4;
    ws = (char*)(((uintptr_t)ws + 255) & ~(uintptr_t)255);
    int*            pairs = (int*)ws;              // E ints        (phase 1)
    unsigned short* hpb   = (unsigned short*)ws;   // n*64 bf16     (phase 2)

    count_kernel      <<<NBLK, 256, 0, stream>>>(col, blkcnt, E, NBLK, NB);
    scan_fused_kernel <<<1, 1024, 0, stream>>>(blkcnt, blkoff, bucket_start, TOT, NBLK, NB, E);
    place_kernel      <<<NBLK, 256, 0, stream>>>(row, col, blkoff, pairs, E, NBLK, NB);
    bucket_sort_kernel<<<NB, 256, 0, stream>>>(bucket_start, pairs, csr_row, row_start, dinv, n, E);
    gemm_kernel       <<<(n + 63) / 64, 256, 0, stream>>>(x, W, dinv, hpb, n);
    aggregate_kernel  <<<(n + 3) / 4, 256, 0, stream>>>(row_start, csr_row, hpb, dinv, b, out, n);
}

// Round 8
// 260.803 us; speedup vs baseline: 1.4193x; 1.4193x over previous
//
#include <hip/hip_runtime.h>
#include <hip/hip_bf16.h>

// GCNConv: out = D^-1/2 (A+I) D^-1/2 (X W) + b
// N=100000, E=1600000, IN=128, OUT=64. edge_index int32, [row(E) | col(E)].
//
// Pipeline v6 — 9 kernels, bf16 hp, multi-block scan (v5's single-block
// fused scan was a 125 µs latency chain — one CU, serial per-thread walk):
//   1. count:       per-block LDS histogram over 782 buckets -> blkcnt[bucket][block]
//   2-4. scan1/2/3: multi-block exclusive scan blkcnt -> blkoff
//   5. bstart:      bucket_start[b] = blkoff[b*NBLK]
//   6. place:       pairs[pos] = row | lcol<<17 (LDS cursors, no global atomics)
//   7. bucket_sort: in-LDS counting sort per bucket -> csr_row (coalesced),
//                   row_start, dinv
//   8. gemm:        hp_bf16 = (x @ W) * dinv[row]   (overlays pairs)
//   9. aggregate:   wave per node, 8-deep bf16 gather unroll

#define IN_CH 128
#define OUT_CH 64
#define BSHIFT 7            // 128 nodes per bucket
#define BNODES 128
#define MAX_NB 800
#define CH_EDGES 16384      // edges per partition block
#define SORT_CAP 4096       // LDS sort capacity (avg bucket = 2046 edges)

__device__ __forceinline__ float b2f(unsigned short u) {
    union { unsigned int i; float f; } v; v.i = (unsigned int)u << 16; return v.f;
}
__device__ __forceinline__ unsigned short f2b(float f) {   // RNE
    unsigned int u = __float_as_uint(f);
    return (unsigned short)((u + 0x7FFFu + ((u >> 16) & 1u)) >> 16);
}

// ---------------- 1: per-block bucket histogram ----------------
__global__ __launch_bounds__(256) void count_kernel(const int* __restrict__ col,
                                                    int* __restrict__ blkcnt,
                                                    int E, int NBLK, int NB) {
    __shared__ int h[MAX_NB];
    int tid = threadIdx.x;
    for (int i = tid; i < NB; i += 256) h[i] = 0;
    __syncthreads();
    int e0 = blockIdx.x * CH_EDGES;
    #pragma unroll 4
    for (int r = 0; r < CH_EDGES / 256; ++r) {
        int e = e0 + r * 256 + tid;
        if (e < E) atomicAdd(&h[col[e] >> BSHIFT], 1);
    }
    __syncthreads();
    for (int i = tid; i < NB; i += 256) blkcnt[i * NBLK + blockIdx.x] = h[i];
}

// ---------------- 2-4: multi-block exclusive scan ----------------
__global__ __launch_bounds__(256) void scan1_kernel(const int* __restrict__ v_in,
                                                    int* __restrict__ partial, int n) {
    __shared__ int s[256];
    int tid = threadIdx.x;
    int i   = blockIdx.x * 256 + tid;
    int v   = (i < n) ? v_in[i] : 0;
    s[tid] = v; __syncthreads();
    #pragma unroll
    for (int off = 1; off < 256; off <<= 1) {
        int t = (tid >= off) ? s[tid - off] : 0;
        __syncthreads();
        s[tid] += t;
        __syncthreads();
    }
    if (tid == 255) partial[blockIdx.x] = s[255];
}

__global__ __launch_bounds__(512) void scan2_kernel(int* __restrict__ partial, int nb) {
    __shared__ int s[512];
    int tid = threadIdx.x;
    int v   = (tid < nb) ? partial[tid] : 0;
    s[tid] = v; __syncthreads();
    #pragma unroll
    for (int off = 1; off < 512; off <<= 1) {
        int t = (tid >= off) ? s[tid - off] : 0;
        __syncthreads();
        s[tid] += t;
        __syncthreads();
    }
    if (tid < nb) partial[tid] = s[tid] - v;   // exclusive
}

__global__ __launch_bounds__(256) void scan3_kernel(const int* __restrict__ v_in,
                                                    const int* __restrict__ partial,
                                                    int* __restrict__ v_out, int n) {
    __shared__ int s[256];
    int tid = threadIdx.x;
    int i   = blockIdx.x * 256 + tid;
    int v   = (i < n) ? v_in[i] : 0;
    s[tid] = v; __syncthreads();
    #pragma unroll
    for (int off = 1; off < 256; off <<= 1) {
        int t = (tid >= off) ? s[tid - off] : 0;
        __syncthreads();
        s[tid] += t;
        __syncthreads();
    }
    if (i < n) v_out[i] = partial[blockIdx.x] + s[tid] - v;  // exclusive
}

__global__ __launch_bounds__(256) void bstart_kernel(const int* __restrict__ blkoff,
                                                     int* __restrict__ bucket_start,
                                                     int NB, int NBLK, int E) {
    int i = blockIdx.x * 256 + threadIdx.x;
    if (i < NB)  bucket_start[i]  = blkoff[i * NBLK];
    if (i == NB) bucket_start[NB] = E;
}

// ---------------- 6: place into pairs (no global atomics) ----------------
__global__ __launch_bounds__(256) void place_kernel(const int* __restrict__ row,
                                                    const int* __restrict__ col,
                                                    const int* __restrict__ blkoff,
                                                    int* __restrict__ pairs,
                                                    int E, int NBLK, int NB) {
    __shared__ int cur[MAX_NB];
    int tid = threadIdx.x;
    for (int i = tid; i < NB; i += 256) cur[i] = blkoff[i * NBLK + blockIdx.x];
    __syncthreads();
    int e0 = blockIdx.x * CH_EDGES;
    #pragma unroll 4
    for (int r2 = 0; r2 < CH_EDGES / 256; ++r2) {
        int e = e0 + r2 * 256 + tid;
        if (e < E) {
            int c = col[e];
            int b = c >> BSHIFT;
            int pos = atomicAdd(&cur[b], 1);          // LDS atomic
            pairs[pos] = row[e] | ((c & (BNODES - 1)) << 17);   // n < 2^17
        }
    }
}

// ---------------- 7: per-bucket in-LDS counting sort ----------------
// Emits: csr_row (node-sorted, coalesced writes), row_start, dinv.
__global__ __launch_bounds__(256) void bucket_sort_kernel(
    const int* __restrict__ bucket_start, const int* __restrict__ pairs,
    int* __restrict__ csr_row, int* __restrict__ row_start,
    float* __restrict__ dinv, int n, int E)
{
    __shared__ int cnt[BNODES];      // counts -> inclusive scan
    __shared__ int deg[BNODES];
    __shared__ int cur[BNODES];
    __shared__ int sorted[SORT_CAP];

    int b = blockIdx.x, tid = threadIdx.x;
    int node0 = b << BSHIFT;
    int nodeCnt = min(BNODES, n - node0);
    int s0 = bucket_start[b], s1 = bucket_start[b + 1];
    int m = s1 - s0;

    if (tid < BNODES) cnt[tid] = 0;
    __syncthreads();
    for (int e = s0 + tid; e < s1; e += 256) atomicAdd(&cnt[pairs[e] >> 17], 1);
    __syncthreads();
    if (tid < BNODES) deg[tid] = cnt[tid];
    __syncthreads();
    #pragma unroll
    for (int off = 1; off < BNODES; off <<= 1) {      // inclusive scan over 128
        int t = (tid >= off && tid < BNODES) ? cnt[tid - off] : 0;
        __syncthreads();
        if (tid < BNODES) cnt[tid] += t;
        __syncthreads();
    }
    if (tid < BNODES) {
        int excl = cnt[tid] - deg[tid];
        cur[tid] = excl;
        if (tid < nodeCnt) {
            row_start[node0 + tid] = s0 + excl;
            dinv[node0 + tid] = rsqrtf((float)(deg[tid] + 1));   // +1 self loop
        }
    }
    if (b == gridDim.x - 1 && tid == 0) row_start[n] = E;
    __syncthreads();

    if (m <= SORT_CAP) {
        for (int e = s0 + tid; e < s1; e += 256) {
            int p   = pairs[e];
            int pos = atomicAdd(&cur[p >> 17], 1);
            sorted[pos] = p & 0x1FFFF;
        }
        __syncthreads();
        for (int i = tid; i < m; i += 256) csr_row[s0 + i] = sorted[i];
    } else {   // fallback: direct global scatter (statistically unreachable)
        if (tid < BNODES) cur[tid] += s0;
        __syncthreads();
        for (int e = s0 + tid; e < s1; e += 256) {
            int p   = pairs[e];
            int pos = atomicAdd(&cur[p >> 17], 1);
            csr_row[pos] = p & 0x1FFFF;
        }
    }
}

// ---------------- 8: GEMM hp_bf16 = (x @ W) * dinv[row] ----------------
__device__ __forceinline__ void fma4(float4& a, float s, const float4& v) {
    a.x = fmaf(s, v.x, a.x);
    a.y = fmaf(s, v.y, a.y);
    a.z = fmaf(s, v.z, a.z);
    a.w = fmaf(s, v.w, a.w);
}

__global__ __launch_bounds__(256) void gemm_kernel(
    const float* __restrict__ x, const float* __restrict__ W,
    const float* __restrict__ dinv, unsigned short* __restrict__ hpb, int n)
{
    __shared__ float xl[64 * 128];   // 32 KB, XOR-swizzled float4 chunks
    __shared__ float wl[128 * 64];   // 32 KB, linear k*64+c

    int tid  = threadIdx.x;
    int row0 = blockIdx.x * 64;

    {
        const float4* wg = (const float4*)W;
        float4* wls = (float4*)wl;
        #pragma unroll
        for (int i = 0; i < 8; ++i) wls[tid + i * 256] = wg[tid + i * 256];
    }
    {
        float4* xls = (float4*)xl;
        #pragma unroll
        for (int i = 0; i < 8; ++i) {
            int f  = tid + i * 256;
            int r  = f >> 5;
            int c0 = f & 31;
            int gr = row0 + r;
            float4 v = make_float4(0.f, 0.f, 0.f, 0.f);
            if (gr < n) v = ((const float4*)(x + (size_t)gr * IN_CH))[c0];
            xls[(r << 5) | (c0 ^ (r & 7))] = v;
        }
    }
    __syncthreads();

    int tr = tid & 15;
    int tc = tid >> 4;

    float4 acc0 = {0,0,0,0}, acc1 = {0,0,0,0}, acc2 = {0,0,0,0}, acc3 = {0,0,0,0};
    const float4* xl4 = (const float4*)xl;
    const float4* wl4 = (const float4*)wl;

    #pragma unroll 4
    for (int k4 = 0; k4 < 32; ++k4) {
        int sc = k4 ^ (tr & 7);
        float4 xa0 = xl4[((tr     ) << 5) | sc];
        float4 xa1 = xl4[((tr + 16) << 5) | sc];
        float4 xa2 = xl4[((tr + 32) << 5) | sc];
        float4 xa3 = xl4[((tr + 48) << 5) | sc];
        float4 wb0 = wl4[((k4 * 4 + 0) << 4) | tc];
        float4 wb1 = wl4[((k4 * 4 + 1) << 4) | tc];
        float4 wb2 = wl4[((k4 * 4 + 2) << 4) | tc];
        float4 wb3 = wl4[((k4 * 4 + 3) << 4) | tc];

        fma4(acc0, xa0.x, wb0); fma4(acc0, xa0.y, wb1); fma4(acc0, xa0.z, wb2); fma4(acc0, xa0.w, wb3);
        fma4(acc1, xa1.x, wb0); fma4(acc1, xa1.y, wb1); fma4(acc1, xa1.z, wb2); fma4(acc1, xa1.w, wb3);
        fma4(acc2, xa2.x, wb0); fma4(acc2, xa2.y, wb1); fma4(acc2, xa2.z, wb2); fma4(acc2, xa2.w, wb3);
        fma4(acc3, xa3.x, wb0); fma4(acc3, xa3.y, wb1); fma4(acc3, xa3.z, wb2); fma4(acc3, xa3.w, wb3);
    }

    float4 accs[4] = {acc0, acc1, acc2, acc3};
    #pragma unroll
    for (int i = 0; i < 4; ++i) {
        int gr = row0 + tr + 16 * i;
        if (gr < n) {
            float di = dinv[gr];
            float4 a = accs[i];
            ushort4 h4;
            h4.x = f2b(a.x * di); h4.y = f2b(a.y * di);
            h4.z = f2b(a.z * di); h4.w = f2b(a.w * di);
            ((ushort4*)(hpb + (size_t)gr * OUT_CH))[tc] = h4;
        }
    }
}

// ---------------- 9: aggregate, bf16 gathers --------------------------------
__global__ __launch_bounds__(256) void aggregate_kernel(
    const int* __restrict__ row_start, const int* __restrict__ csr_row,
    const unsigned short* __restrict__ hpb, const float* __restrict__ dinv,
    const float* __restrict__ bias, float* __restrict__ out, int n)
{
    int wid  = (blockIdx.x * 256 + threadIdx.x) >> 6;   // node id
    int lane = threadIdx.x & 63;
    if (wid >= n) return;

    int s0 = row_start[wid];
    int s1 = row_start[wid + 1];

    float self = b2f(hpb[(size_t)wid * OUT_CH + lane]);
    float a0 = 0.f, a1 = 0.f, a2 = 0.f, a3 = 0.f;
    float a4 = 0.f, a5 = 0.f, a6 = 0.f, a7 = 0.f;

    for (int base = s0; base < s1; base += 64) {
        int cnt  = min(64, s1 - base);
        int ridx = (base + lane < s1) ? csr_row[base + lane] : 0;
        int j = 0;
        for (; j + 8 <= cnt; j += 8) {
            int r0 = __shfl(ridx, j);
            int r1 = __shfl(ridx, j + 1);
            int r2 = __shfl(ridx, j + 2);
            int r3 = __shfl(ridx, j + 3);
            int r4 = __shfl(ridx, j + 4);
            int r5 = __shfl(ridx, j + 5);
            int r6 = __shfl(ridx, j + 6);
            int r7 = __shfl(ridx, j + 7);
            a0 += b2f(hpb[(size_t)r0 * OUT_CH + lane]);
            a1 += b2f(hpb[(size_t)r1 * OUT_CH + lane]);
            a2 += b2f(hpb[(size_t)r2 * OUT_CH + lane]);
            a3 += b2f(hpb[(size_t)r3 * OUT_CH + lane]);
            a4 += b2f(hpb[(size_t)r4 * OUT_CH + lane]);
            a5 += b2f(hpb[(size_t)r5 * OUT_CH + lane]);
            a6 += b2f(hpb[(size_t)r6 * OUT_CH + lane]);
            a7 += b2f(hpb[(size_t)r7 * OUT_CH + lane]);
        }
        for (; j < cnt; ++j) {
            int r = __shfl(ridx, j);
            a0 += b2f(hpb[(size_t)r * OUT_CH + lane]);
        }
    }
    float acc = self + (((a0 + a1) + (a2 + a3)) + ((a4 + a5) + (a6 + a7)));
    out[(size_t)wid * OUT_CH + lane] = fmaf(dinv[wid], acc, bias[lane]);
}

extern "C" void kernel_launch(void* const* d_in, const int* in_sizes, int n_in,
                              void* d_out, int out_size, void* d_ws, size_t ws_size,
                              hipStream_t stream) {
    const float* x  = (const float*)d_in[0];
    const int*   ei = (const int*)d_in[1];
    const float* W  = (const float*)d_in[2];
    const float* b  = (const float*)d_in[3];
    float*       out = (float*)d_out;

    int n = in_sizes[0] / IN_CH;     // 100000
    int E = in_sizes[1] / 2;         // 1600000
    const int* row = ei;
    const int* col = ei + E;

    int NB   = (n + BNODES - 1) >> BSHIFT;           // 782
    int NBLK = (E + CH_EDGES - 1) / CH_EDGES;        // 98
    int TOT  = NB * NBLK;                            // 76636
    int nbs  = (TOT + 255) / 256;                    // 300 (<=512)

    // workspace layout; hpb (bf16, n*64) overlays pairs (dead after bucket_sort)
    char* ws = (char*)d_ws;
    int*   blkcnt       = (int*)ws;   ws += (size_t)TOT * 4;
    int*   blkoff       = (int*)ws;   ws += (size_t)TOT * 4;
    int*   partial      = (int*)ws;   ws += 512 * 4;
    int*   bucket_start = (int*)ws;   ws += (size_t)(NB + 1) * 4;
    int*   row_start    = (int*)ws;   ws += (size_t)(n + 1) * 4;
    float* dinv         = (float*)ws; ws += (size_t)n * 4;
    int*   csr_row      = (int*)ws;   ws += (size_t)E * 4;
    ws = (char*)(((uintptr_t)ws + 255) & ~(uintptr_t)255);
    int*            pairs = (int*)ws;              // E ints        (phase 1)
    unsigned short* hpb   = (unsigned short*)ws;   // n*64 bf16     (phase 2)

    count_kernel      <<<NBLK, 256, 0, stream>>>(col, blkcnt, E, NBLK, NB);
    scan1_kernel      <<<nbs, 256, 0, stream>>>(blkcnt, partial, TOT);
    scan2_kernel      <<<1, 512, 0, stream>>>(partial, nbs);
    scan3_kernel      <<<nbs, 256, 0, stream>>>(blkcnt, partial, blkoff, TOT);
    bstart_kernel     <<<(NB + 256) / 256, 256, 0, stream>>>(blkoff, bucket_start, NB, NBLK, E);
    place_kernel      <<<NBLK, 256, 0, stream>>>(row, col, blkoff, pairs, E, NBLK, NB);
    bucket_sort_kernel<<<NB, 256, 0, stream>>>(bucket_start, pairs, csr_row, row_start, dinv, n, E);
    gemm_kernel       <<<(n + 63) / 64, 256, 0, stream>>>(x, W, dinv, hpb, n);
    aggregate_kernel  <<<(n + 3) / 4, 256, 0, stream>>>(row_start, csr_row, hpb, dinv, b, out, n);
}

// Round 9
// 208.297 us; speedup vs baseline: 1.7771x; 1.2521x over previous
//
#include <hip/hip_runtime.h>
#include <hip/hip_bf16.h>

// GCNConv: out = D^-1/2 (A+I) D^-1/2 (X W) + b
// N=100000, E=1600000, IN=128, OUT=64. edge_index int32, [row(E) | col(E)].
//
// Pipeline v7 — 8 kernels:
//   1. count:       1024-thr blocks, LDS histogram -> blkcnt[bucket][block]
//   2-4. scan1/2/3: multi-block exclusive scan blkcnt -> blkoff (+bucket_start)
//   5. place:       1024-thr blocks, pairs[pos] = row | lcol<<17 (LDS cursors)
//   6. bucket_sort: in-LDS counting sort per bucket -> csr_row, row_start, dinv
//   7. gemm:        hp_bf16 = (x @ W) * dinv[row]   (overlays pairs)
//   8. aggregate:   wave per node, 2 edges/wave in half-waves, uint bf16x2 gathers

#define IN_CH 128
#define OUT_CH 64
#define BSHIFT 7            // 128 nodes per bucket
#define BNODES 128
#define MAX_NB 800
#define CH_EDGES 7168       // edges per partition block (7 rounds x 1024 thr)
#define SORT_CAP 4096       // LDS sort capacity (avg bucket = 2046 edges)

__device__ __forceinline__ unsigned short f2b(float f) {   // RNE
    unsigned int u = __float_as_uint(f);
    return (unsigned short)((u + 0x7FFFu + ((u >> 16) & 1u)) >> 16);
}

// ---------------- 1: per-block bucket histogram (1024 thr) ----------------
__global__ __launch_bounds__(1024) void count_kernel(const int* __restrict__ col,
                                                     int* __restrict__ blkcnt,
                                                     int E, int NBLK, int NB) {
    __shared__ int h[MAX_NB];
    int tid = threadIdx.x;
    for (int i = tid; i < NB; i += 1024) h[i] = 0;
    __syncthreads();
    int e0 = blockIdx.x * CH_EDGES;
    #pragma unroll
    for (int r = 0; r < CH_EDGES / 1024; ++r) {
        int e = e0 + r * 1024 + tid;
        if (e < E) atomicAdd(&h[col[e] >> BSHIFT], 1);
    }
    __syncthreads();
    for (int i = tid; i < NB; i += 1024) blkcnt[i * NBLK + blockIdx.x] = h[i];
}

// ---------------- 2-4: multi-block exclusive scan ----------------
__global__ __launch_bounds__(256) void scan1_kernel(const int* __restrict__ v_in,
                                                    int* __restrict__ partial, int n) {
    __shared__ int s[256];
    int tid = threadIdx.x;
    int i   = blockIdx.x * 256 + tid;
    int v   = (i < n) ? v_in[i] : 0;
    s[tid] = v; __syncthreads();
    #pragma unroll
    for (int off = 1; off < 256; off <<= 1) {
        int t = (tid >= off) ? s[tid - off] : 0;
        __syncthreads();
        s[tid] += t;
        __syncthreads();
    }
    if (tid == 255) partial[blockIdx.x] = s[255];
}

__global__ __launch_bounds__(1024) void scan2_kernel(int* __restrict__ partial, int nb) {
    __shared__ int s[1024];
    int tid = threadIdx.x;
    int v   = (tid < nb) ? partial[tid] : 0;
    s[tid] = v; __syncthreads();
    #pragma unroll
    for (int off = 1; off < 1024; off <<= 1) {
        int t = (tid >= off) ? s[tid - off] : 0;
        __syncthreads();
        s[tid] += t;
        __syncthreads();
    }
    if (tid < nb) partial[tid] = s[tid] - v;   // exclusive
}

// scan3 + fused bucket_start extraction (bucket_start[b] = blkoff[b*NBLK])
__global__ __launch_bounds__(256) void scan3_kernel(const int* __restrict__ v_in,
                                                    const int* __restrict__ partial,
                                                    int* __restrict__ v_out,
                                                    int* __restrict__ bucket_start,
                                                    int n, int NBLK, int NB, int E) {
    __shared__ int s[256];
    int tid = threadIdx.x;
    int i   = blockIdx.x * 256 + tid;
    int v   = (i < n) ? v_in[i] : 0;
    s[tid] = v; __syncthreads();
    #pragma unroll
    for (int off = 1; off < 256; off <<= 1) {
        int t = (tid >= off) ? s[tid - off] : 0;
        __syncthreads();
        s[tid] += t;
        __syncthreads();
    }
    if (i < n) {
        int excl = partial[blockIdx.x] + s[tid] - v;
        v_out[i] = excl;
        if (i % NBLK == 0) bucket_start[i / NBLK] = excl;
    }
    if (i == 0) bucket_start[NB] = E;
}

// ---------------- 5: place into pairs (1024 thr, no global atomics) ---------
__global__ __launch_bounds__(1024) void place_kernel(const int* __restrict__ row,
                                                     const int* __restrict__ col,
                                                     const int* __restrict__ blkoff,
                                                     int* __restrict__ pairs,
                                                     int E, int NBLK, int NB) {
    __shared__ int cur[MAX_NB];
    int tid = threadIdx.x;
    for (int i = tid; i < NB; i += 1024) cur[i] = blkoff[i * NBLK + blockIdx.x];
    __syncthreads();
    int e0 = blockIdx.x * CH_EDGES;
    #pragma unroll
    for (int r2 = 0; r2 < CH_EDGES / 1024; ++r2) {
        int e = e0 + r2 * 1024 + tid;
        if (e < E) {
            int c = col[e];
            int b = c >> BSHIFT;
            int pos = atomicAdd(&cur[b], 1);          // LDS atomic
            pairs[pos] = row[e] | ((c & (BNODES - 1)) << 17);   // n < 2^17
        }
    }
}

// ---------------- 6: per-bucket in-LDS counting sort ----------------
__global__ __launch_bounds__(256) void bucket_sort_kernel(
    const int* __restrict__ bucket_start, const int* __restrict__ pairs,
    int* __restrict__ csr_row, int* __restrict__ row_start,
    float* __restrict__ dinv, int n, int E)
{
    __shared__ int cnt[BNODES];      // counts -> inclusive scan
    __shared__ int deg[BNODES];
    __shared__ int cur[BNODES];
    __shared__ int sorted[SORT_CAP];

    int b = blockIdx.x, tid = threadIdx.x;
    int node0 = b << BSHIFT;
    int nodeCnt = min(BNODES, n - node0);
    int s0 = bucket_start[b], s1 = bucket_start[b + 1];
    int m = s1 - s0;

    if (tid < BNODES) cnt[tid] = 0;
    __syncthreads();
    for (int e = s0 + tid; e < s1; e += 256) atomicAdd(&cnt[pairs[e] >> 17], 1);
    __syncthreads();
    if (tid < BNODES) deg[tid] = cnt[tid];
    __syncthreads();
    #pragma unroll
    for (int off = 1; off < BNODES; off <<= 1) {      // inclusive scan over 128
        int t = (tid >= off && tid < BNODES) ? cnt[tid - off] : 0;
        __syncthreads();
        if (tid < BNODES) cnt[tid] += t;
        __syncthreads();
    }
    if (tid < BNODES) {
        int excl = cnt[tid] - deg[tid];
        cur[tid] = excl;
        if (tid < nodeCnt) {
            row_start[node0 + tid] = s0 + excl;
            dinv[node0 + tid] = rsqrtf((float)(deg[tid] + 1));   // +1 self loop
        }
    }
    if (b == gridDim.x - 1 && tid == 0) row_start[n] = E;
    __syncthreads();

    if (m <= SORT_CAP) {
        for (int e = s0 + tid; e < s1; e += 256) {
            int p   = pairs[e];
            int pos = atomicAdd(&cur[p >> 17], 1);
            sorted[pos] = p & 0x1FFFF;
        }
        __syncthreads();
        for (int i = tid; i < m; i += 256) csr_row[s0 + i] = sorted[i];
    } else {   // fallback: direct global scatter (statistically unreachable)
        if (tid < BNODES) cur[tid] += s0;
        __syncthreads();
        for (int e = s0 + tid; e < s1; e += 256) {
            int p   = pairs[e];
            int pos = atomicAdd(&cur[p >> 17], 1);
            csr_row[pos] = p & 0x1FFFF;
        }
    }
}

// ---------------- 7: GEMM hp_bf16 = (x @ W) * dinv[row] ----------------
__device__ __forceinline__ void fma4(float4& a, float s, const float4& v) {
    a.x = fmaf(s, v.x, a.x);
    a.y = fmaf(s, v.y, a.y);
    a.z = fmaf(s, v.z, a.z);
    a.w = fmaf(s, v.w, a.w);
}

__global__ __launch_bounds__(256) void gemm_kernel(
    const float* __restrict__ x, const float* __restrict__ W,
    const float* __restrict__ dinv, unsigned short* __restrict__ hpb, int n)
{
    __shared__ float xl[64 * 128];   // 32 KB, XOR-swizzled float4 chunks
    __shared__ float wl[128 * 64];   // 32 KB, linear k*64+c

    int tid  = threadIdx.x;
    int row0 = blockIdx.x * 64;

    {
        const float4* wg = (const float4*)W;
        float4* wls = (float4*)wl;
        #pragma unroll
        for (int i = 0; i < 8; ++i) wls[tid + i * 256] = wg[tid + i * 256];
    }
    {
        float4* xls = (float4*)xl;
        #pragma unroll
        for (int i = 0; i < 8; ++i) {
            int f  = tid + i * 256;
            int r  = f >> 5;
            int c0 = f & 31;
            int gr = row0 + r;
            float4 v = make_float4(0.f, 0.f, 0.f, 0.f);
            if (gr < n) v = ((const float4*)(x + (size_t)gr * IN_CH))[c0];
            xls[(r << 5) | (c0 ^ (r & 7))] = v;
        }
    }
    __syncthreads();

    int tr = tid & 15;
    int tc = tid >> 4;

    float4 acc0 = {0,0,0,0}, acc1 = {0,0,0,0}, acc2 = {0,0,0,0}, acc3 = {0,0,0,0};
    const float4* xl4 = (const float4*)xl;
    const float4* wl4 = (const float4*)wl;

    #pragma unroll 4
    for (int k4 = 0; k4 < 32; ++k4) {
        int sc = k4 ^ (tr & 7);
        float4 xa0 = xl4[((tr     ) << 5) | sc];
        float4 xa1 = xl4[((tr + 16) << 5) | sc];
        float4 xa2 = xl4[((tr + 32) << 5) | sc];
        float4 xa3 = xl4[((tr + 48) << 5) | sc];
        float4 wb0 = wl4[((k4 * 4 + 0) << 4) | tc];
        float4 wb1 = wl4[((k4 * 4 + 1) << 4) | tc];
        float4 wb2 = wl4[((k4 * 4 + 2) << 4) | tc];
        float4 wb3 = wl4[((k4 * 4 + 3) << 4) | tc];

        fma4(acc0, xa0.x, wb0); fma4(acc0, xa0.y, wb1); fma4(acc0, xa0.z, wb2); fma4(acc0, xa0.w, wb3);
        fma4(acc1, xa1.x, wb0); fma4(acc1, xa1.y, wb1); fma4(acc1, xa1.z, wb2); fma4(acc1, xa1.w, wb3);
        fma4(acc2, xa2.x, wb0); fma4(acc2, xa2.y, wb1); fma4(acc2, xa2.z, wb2); fma4(acc2, xa2.w, wb3);
        fma4(acc3, xa3.x, wb0); fma4(acc3, xa3.y, wb1); fma4(acc3, xa3.z, wb2); fma4(acc3, xa3.w, wb3);
    }

    float4 accs[4] = {acc0, acc1, acc2, acc3};
    #pragma unroll
    for (int i = 0; i < 4; ++i) {
        int gr = row0 + tr + 16 * i;
        if (gr < n) {
            float di = dinv[gr];
            float4 a = accs[i];
            ushort4 h4;
            h4.x = f2b(a.x * di); h4.y = f2b(a.y * di);
            h4.z = f2b(a.z * di); h4.w = f2b(a.w * di);
            ((ushort4*)(hpb + (size_t)gr * OUT_CH))[tc] = h4;
        }
    }
}

// ---------------- 8: aggregate — 2 edges/wave via half-waves ----------------
// Lane l<32: channels {2l,2l+1} of even-offset edges; lane l>=32: odd edges.
// Gather = uint (2 bf16); cross-half __shfl_xor(32) combine; float2 store.
__global__ __launch_bounds__(256) void aggregate_kernel(
    const int* __restrict__ row_start, const int* __restrict__ csr_row,
    const unsigned short* __restrict__ hpb, const float* __restrict__ dinv,
    const float* __restrict__ bias, float* __restrict__ out, int n)
{
    int wid  = (blockIdx.x * 256 + threadIdx.x) >> 6;   // node id
    int lane = threadIdx.x & 63;
    if (wid >= n) return;
    int half = lane >> 5;      // which edge of the pair
    int hl   = lane & 31;      // channel-pair index

    const unsigned int* hp32 = (const unsigned int*)hpb;   // row stride 32 uints

    int s0 = row_start[wid];
    int s1 = row_start[wid + 1];

    float a0l=0.f,a0h=0.f,a1l=0.f,a1h=0.f,a2l=0.f,a2h=0.f,a3l=0.f,a3h=0.f;

    for (int base = s0; base < s1; base += 64) {
        int cnt  = min(64, s1 - base);
        int ridx = (base + lane < s1) ? csr_row[base + lane] : 0;
        int j = 0;
        for (; j + 8 <= cnt; j += 8) {      // 8 edges: 4 per half-wave
            int r0 = __shfl(ridx, j     + half);
            int r1 = __shfl(ridx, j + 2 + half);
            int r2 = __shfl(ridx, j + 4 + half);
            int r3 = __shfl(ridx, j + 6 + half);
            unsigned int v0 = hp32[(size_t)r0 * 32 + hl];
            unsigned int v1 = hp32[(size_t)r1 * 32 + hl];
            unsigned int v2 = hp32[(size_t)r2 * 32 + hl];
            unsigned int v3 = hp32[(size_t)r3 * 32 + hl];
            a0l += __uint_as_float(v0 << 16); a0h += __uint_as_float(v0 & 0xFFFF0000u);
            a1l += __uint_as_float(v1 << 16); a1h += __uint_as_float(v1 & 0xFFFF0000u);
            a2l += __uint_as_float(v2 << 16); a2h += __uint_as_float(v2 & 0xFFFF0000u);
            a3l += __uint_as_float(v3 << 16); a3h += __uint_as_float(v3 & 0xFFFF0000u);
        }
        for (; j < cnt; j += 2) {           // tail: up to 2 edges at a time
            int e = j + half;
            int r = __shfl(ridx, e);        // OOB lanes of ridx hold 0 -> safe row
            unsigned int v = (e < cnt) ? hp32[(size_t)r * 32 + hl] : 0u;
            a0l += __uint_as_float(v << 16); a0h += __uint_as_float(v & 0xFFFF0000u);
        }
    }
    float sl = ((a0l + a1l) + (a2l + a3l));
    float sh = ((a0h + a1h) + (a2h + a3h));
    sl += __shfl_xor(sl, 32);
    sh += __shfl_xor(sh, 32);

    if (half == 0) {
        unsigned int sv = hp32[(size_t)wid * 32 + hl];   // self loop
        sl += __uint_as_float(sv << 16);
        sh += __uint_as_float(sv & 0xFFFF0000u);
        float d = dinv[wid];
        float2 bb = ((const float2*)bias)[hl];
        float2 o;
        o.x = fmaf(d, sl, bb.x);
        o.y = fmaf(d, sh, bb.y);
        ((float2*)(out + (size_t)wid * OUT_CH))[hl] = o;
    }
}

extern "C" void kernel_launch(void* const* d_in, const int* in_sizes, int n_in,
                              void* d_out, int out_size, void* d_ws, size_t ws_size,
                              hipStream_t stream) {
    const float* x  = (const float*)d_in[0];
    const int*   ei = (const int*)d_in[1];
    const float* W  = (const float*)d_in[2];
    const float* b  = (const float*)d_in[3];
    float*       out = (float*)d_out;

    int n = in_sizes[0] / IN_CH;     // 100000
    int E = in_sizes[1] / 2;         // 1600000
    const int* row = ei;
    const int* col = ei + E;

    int NB   = (n + BNODES - 1) >> BSHIFT;           // 782
    int NBLK = (E + CH_EDGES - 1) / CH_EDGES;        // 224
    int TOT  = NB * NBLK;                            // 175168
    int nbs  = (TOT + 255) / 256;                    // 685 (<=1024)

    // workspace layout; hpb (bf16, n*64) overlays pairs (dead after bucket_sort)
    char* ws = (char*)d_ws;
    int*   blkcnt       = (int*)ws;   ws += (size_t)TOT * 4;
    int*   blkoff       = (int*)ws;   ws += (size_t)TOT * 4;
    int*   partial      = (int*)ws;   ws += 1024 * 4;
    int*   bucket_start = (int*)ws;   ws += (size_t)(NB + 1) * 4;
    int*   row_start    = (int*)ws;   ws += (size_t)(n + 1) * 4;
    float* dinv         = (float*)ws; ws += (size_t)n * 4;
    int*   csr_row      = (int*)ws;   ws += (size_t)E * 4;
    ws = (char*)(((uintptr_t)ws + 255) & ~(uintptr_t)255);
    int*            pairs = (int*)ws;              // E ints        (phase 1)
    unsigned short* hpb   = (unsigned short*)ws;   // n*64 bf16     (phase 2)

    count_kernel      <<<NBLK, 1024, 0, stream>>>(col, blkcnt, E, NBLK, NB);
    scan1_kernel      <<<nbs, 256, 0, stream>>>(blkcnt, partial, TOT);
    scan2_kernel      <<<1, 1024, 0, stream>>>(partial, nbs);
    scan3_kernel      <<<nbs, 256, 0, stream>>>(blkcnt, partial, blkoff, bucket_start,
                                                TOT, NBLK, NB, E);
    place_kernel      <<<NBLK, 1024, 0, stream>>>(row, col, blkoff, pairs, E, NBLK, NB);
    bucket_sort_kernel<<<NB, 256, 0, stream>>>(bucket_start, pairs, csr_row, row_start, dinv, n, E);
    gemm_kernel       <<<(n + 63) / 64, 256, 0, stream>>>(x, W, dinv, hpb, n);
    aggregate_kernel  <<<(n + 3) / 4, 256, 0, stream>>>(row_start, csr_row, hpb, dinv, b, out, n);
}

// Round 11
// 184.815 us; speedup vs baseline: 2.0029x; 1.1271x over previous
//
#include <hip/hip_runtime.h>
#include <hip/hip_bf16.h>

// GCNConv: out = D^-1/2 (A+I) D^-1/2 (X W) + b
// N=100000, E=1600000, IN=128, OUT=64. edge_index int32, [row(E) | col(E)].
//
// Pipeline v8.1 — MFMA gemm (fix: wl staging covered only k<64; now full 128):
//   0. wprep:       W fp32 [k][n] -> wbt bf16 [n][k]  (16 KB, L2-resident)
//   1. count:       1024-thr blocks, LDS histogram -> blkcnt[bucket][block]
//   2-4. scan1/2/3: multi-block exclusive scan blkcnt -> blkoff (+bucket_start)
//   5. place:       1024-thr blocks, pairs[pos] = row | lcol<<17 (LDS cursors)
//   6. bucket_sort: in-LDS counting sort per bucket -> csr_row, row_start, dinv
//   7. gemm:        MFMA 16x16x32 bf16; hp_bf16 = (dinv[row]*x) @ W (overlays pairs)
//   8. aggregate:   wave per node, 2 edges/wave half-waves, uint bf16x2 gathers

#define IN_CH 128
#define OUT_CH 64
#define BSHIFT 7            // 128 nodes per bucket
#define BNODES 128
#define MAX_NB 800
#define CH_EDGES 7168       // edges per partition block (7 rounds x 1024 thr)
#define SORT_CAP 4096       // LDS sort capacity (avg bucket = 2046 edges)
#define XSTR 136            // bf16 LDS row stride: 272B = 17x16B -> conflict-free b128

typedef short bf16x8 __attribute__((ext_vector_type(8)));
typedef float f32x4  __attribute__((ext_vector_type(4)));

__device__ __forceinline__ unsigned short f2b(float f) {   // RNE fp32->bf16
    unsigned int u = __float_as_uint(f);
    return (unsigned short)((u + 0x7FFFu + ((u >> 16) & 1u)) >> 16);
}

// ---------------- 0: W fp32 [k][n] -> bf16 [n][k] ----------------
__global__ __launch_bounds__(256) void wprep_kernel(const float* __restrict__ W,
                                                    unsigned short* __restrict__ wbt) {
    int t = blockIdx.x * 256 + threadIdx.x;   // 8192 elements
    int k = t >> 6, nn = t & 63;
    wbt[nn * IN_CH + k] = f2b(W[t]);
}

// ---------------- 1: per-block bucket histogram (1024 thr) ----------------
__global__ __launch_bounds__(1024) void count_kernel(const int* __restrict__ col,
                                                     int* __restrict__ blkcnt,
                                                     int E, int NBLK, int NB) {
    __shared__ int h[MAX_NB];
    int tid = threadIdx.x;
    for (int i = tid; i < NB; i += 1024) h[i] = 0;
    __syncthreads();
    int e0 = blockIdx.x * CH_EDGES;
    #pragma unroll
    for (int r = 0; r < CH_EDGES / 1024; ++r) {
        int e = e0 + r * 1024 + tid;
        if (e < E) atomicAdd(&h[col[e] >> BSHIFT], 1);
    }
    __syncthreads();
    for (int i = tid; i < NB; i += 1024) blkcnt[i * NBLK + blockIdx.x] = h[i];
}

// ---------------- 2-4: multi-block exclusive scan ----------------
__global__ __launch_bounds__(256) void scan1_kernel(const int* __restrict__ v_in,
                                                    int* __restrict__ partial, int n) {
    __shared__ int s[256];
    int tid = threadIdx.x;
    int i   = blockIdx.x * 256 + tid;
    int v   = (i < n) ? v_in[i] : 0;
    s[tid] = v; __syncthreads();
    #pragma unroll
    for (int off = 1; off < 256; off <<= 1) {
        int t = (tid >= off) ? s[tid - off] : 0;
        __syncthreads();
        s[tid] += t;
        __syncthreads();
    }
    if (tid == 255) partial[blockIdx.x] = s[255];
}

__global__ __launch_bounds__(1024) void scan2_kernel(int* __restrict__ partial, int nb) {
    __shared__ int s[1024];
    int tid = threadIdx.x;
    int v   = (tid < nb) ? partial[tid] : 0;
    s[tid] = v; __syncthreads();
    #pragma unroll
    for (int off = 1; off < 1024; off <<= 1) {
        int t = (tid >= off) ? s[tid - off] : 0;
        __syncthreads();
        s[tid] += t;
        __syncthreads();
    }
    if (tid < nb) partial[tid] = s[tid] - v;   // exclusive
}

// scan3 + fused bucket_start extraction (bucket_start[b] = blkoff[b*NBLK])
__global__ __launch_bounds__(256) void scan3_kernel(const int* __restrict__ v_in,
                                                    const int* __restrict__ partial,
                                                    int* __restrict__ v_out,
                                                    int* __restrict__ bucket_start,
                                                    int n, int NBLK, int NB, int E) {
    __shared__ int s[256];
    int tid = threadIdx.x;
    int i   = blockIdx.x * 256 + tid;
    int v   = (i < n) ? v_in[i] : 0;
    s[tid] = v; __syncthreads();
    #pragma unroll
    for (int off = 1; off < 256; off <<= 1) {
        int t = (tid >= off) ? s[tid - off] : 0;
        __syncthreads();
        s[tid] += t;
        __syncthreads();
    }
    if (i < n) {
        int excl = partial[blockIdx.x] + s[tid] - v;
        v_out[i] = excl;
        if (i % NBLK == 0) bucket_start[i / NBLK] = excl;
    }
    if (i == 0) bucket_start[NB] = E;
}

// ---------------- 5: place into pairs (1024 thr, no global atomics) ---------
__global__ __launch_bounds__(1024) void place_kernel(const int* __restrict__ row,
                                                     const int* __restrict__ col,
                                                     const int* __restrict__ blkoff,
                                                     int* __restrict__ pairs,
                                                     int E, int NBLK, int NB) {
    __shared__ int cur[MAX_NB];
    int tid = threadIdx.x;
    for (int i = tid; i < NB; i += 1024) cur[i] = blkoff[i * NBLK + blockIdx.x];
    __syncthreads();
    int e0 = blockIdx.x * CH_EDGES;
    #pragma unroll
    for (int r2 = 0; r2 < CH_EDGES / 1024; ++r2) {
        int e = e0 + r2 * 1024 + tid;
        if (e < E) {
            int c = col[e];
            int b = c >> BSHIFT;
            int pos = atomicAdd(&cur[b], 1);          // LDS atomic
            pairs[pos] = row[e] | ((c & (BNODES - 1)) << 17);   // n < 2^17
        }
    }
}

// ---------------- 6: per-bucket in-LDS counting sort ----------------
__global__ __launch_bounds__(256) void bucket_sort_kernel(
    const int* __restrict__ bucket_start, const int* __restrict__ pairs,
    int* __restrict__ csr_row, int* __restrict__ row_start,
    float* __restrict__ dinv, int n, int E)
{
    __shared__ int cnt[BNODES];      // counts -> inclusive scan
    __shared__ int deg[BNODES];
    __shared__ int cur[BNODES];
    __shared__ int sorted[SORT_CAP];

    int b = blockIdx.x, tid = threadIdx.x;
    int node0 = b << BSHIFT;
    int nodeCnt = min(BNODES, n - node0);
    int s0 = bucket_start[b], s1 = bucket_start[b + 1];
    int m = s1 - s0;

    if (tid < BNODES) cnt[tid] = 0;
    __syncthreads();
    for (int e = s0 + tid; e < s1; e += 256) atomicAdd(&cnt[pairs[e] >> 17], 1);
    __syncthreads();
    if (tid < BNODES) deg[tid] = cnt[tid];
    __syncthreads();
    #pragma unroll
    for (int off = 1; off < BNODES; off <<= 1) {      // inclusive scan over 128
        int t = (tid >= off && tid < BNODES) ? cnt[tid - off] : 0;
        __syncthreads();
        if (tid < BNODES) cnt[tid] += t;
        __syncthreads();
    }
    if (tid < BNODES) {
        int excl = cnt[tid] - deg[tid];
        cur[tid] = excl;
        if (tid < nodeCnt) {
            row_start[node0 + tid] = s0 + excl;
            dinv[node0 + tid] = rsqrtf((float)(deg[tid] + 1));   // +1 self loop
        }
    }
    if (b == gridDim.x - 1 && tid == 0) row_start[n] = E;
    __syncthreads();

    if (m <= SORT_CAP) {
        for (int e = s0 + tid; e < s1; e += 256) {
            int p   = pairs[e];
            int pos = atomicAdd(&cur[p >> 17], 1);
            sorted[pos] = p & 0x1FFFF;
        }
        __syncthreads();
        for (int i = tid; i < m; i += 256) csr_row[s0 + i] = sorted[i];
    } else {   // fallback: direct global scatter (statistically unreachable)
        if (tid < BNODES) cur[tid] += s0;
        __syncthreads();
        for (int e = s0 + tid; e < s1; e += 256) {
            int p   = pairs[e];
            int pos = atomicAdd(&cur[p >> 17], 1);
            csr_row[pos] = p & 0x1FFFF;
        }
    }
}

// ---------------- 7: MFMA GEMM  hp_bf16 = (dinv*x) @ W ----------------
// 256 thr = 4 waves; 64-row tile; wave w does rows w*16..w*16+15 x all 64 cols.
// A-frag: lane(m=l&15, k=(l>>4)*8+j); B-frag: lane(n=l&15, k=(l>>4)*8+j);
// C: col=l&15, row=(l>>4)*4+reg  [guide §3, m89/m91].
__global__ __launch_bounds__(256) void gemm_kernel(
    const float* __restrict__ x, const unsigned short* __restrict__ wbt,
    const float* __restrict__ dinv, unsigned short* __restrict__ hpb, int n)
{
    __shared__ __align__(16) unsigned short xl[64 * XSTR];  // 17408 B
    __shared__ __align__(16) unsigned short wl[64 * XSTR];  // W^T: [n][k]

    int tid  = threadIdx.x;
    int row0 = blockIdx.x * 64;

    // stage W^T bf16 from wbt: 1024 x 16B chunks (16 per n-row, full k=0..127)
    {
        const uint4* src = (const uint4*)wbt;
        #pragma unroll
        for (int i = 0; i < 4; ++i) {
            int flat = tid + i * 256;
            int nn = flat >> 4, c = flat & 15;
            *(uint4*)(wl + nn * XSTR + c * 8) = src[flat];
        }
    }
    // stage x rows (scaled by dinv, fp32->bf16): thread covers (row, 8-f chunk)
    #pragma unroll
    for (int i = 0; i < 4; ++i) {
        int r  = (tid >> 4) + i * 16;
        int c  = tid & 15;
        int gr = row0 + r;
        float4 v0 = make_float4(0.f,0.f,0.f,0.f), v1 = v0;
        float d = 0.f;
        if (gr < n) {
            d = dinv[gr];
            const float4* xr = (const float4*)(x + (size_t)gr * IN_CH);
            v0 = xr[c * 2]; v1 = xr[c * 2 + 1];
        }
        uint4 p;
        p.x = ((unsigned)f2b(v0.y * d) << 16) | f2b(v0.x * d);
        p.y = ((unsigned)f2b(v0.w * d) << 16) | f2b(v0.z * d);
        p.z = ((unsigned)f2b(v1.y * d) << 16) | f2b(v1.x * d);
        p.w = ((unsigned)f2b(v1.w * d) << 16) | f2b(v1.z * d);
        *(uint4*)(xl + r * XSTR + c * 8) = p;
    }
    __syncthreads();

    int lane = tid & 63, w = tid >> 6;
    int mrow = lane & 15;      // A row / B col within tile
    int g    = lane >> 4;      // k-subgroup

    f32x4 acc0 = {0,0,0,0}, acc1 = {0,0,0,0}, acc2 = {0,0,0,0}, acc3 = {0,0,0,0};
    const unsigned short* xbase = xl + (w * 16 + mrow) * XSTR + g * 8;
    const unsigned short* wbase = wl + mrow * XSTR + g * 8;

    #pragma unroll
    for (int k4 = 0; k4 < 4; ++k4) {
        bf16x8 a  = *(const bf16x8*)(xbase + k4 * 32);
        bf16x8 b0 = *(const bf16x8*)(wbase +             k4 * 32);
        bf16x8 b1 = *(const bf16x8*)(wbase + 16 * XSTR + k4 * 32);
        bf16x8 b2 = *(const bf16x8*)(wbase + 32 * XSTR + k4 * 32);
        bf16x8 b3 = *(const bf16x8*)(wbase + 48 * XSTR + k4 * 32);
        acc0 = __builtin_amdgcn_mfma_f32_16x16x32_bf16(a, b0, acc0, 0, 0, 0);
        acc1 = __builtin_amdgcn_mfma_f32_16x16x32_bf16(a, b1, acc1, 0, 0, 0);
        acc2 = __builtin_amdgcn_mfma_f32_16x16x32_bf16(a, b2, acc2, 0, 0, 0);
        acc3 = __builtin_amdgcn_mfma_f32_16x16x32_bf16(a, b3, acc3, 0, 0, 0);
    }
    __syncthreads();   // done reading xl; reuse it for the C tile

    {
        int cm = g * 4;
        #pragma unroll
        for (int r = 0; r < 4; ++r) {
            unsigned short* crow = xl + (w * 16 + cm + r) * XSTR + mrow;
            crow[ 0] = f2b(acc0[r]);
            crow[16] = f2b(acc1[r]);
            crow[32] = f2b(acc2[r]);
            crow[48] = f2b(acc3[r]);
        }
    }
    __syncthreads();
    // coalesced bf16 write-out: 512 x 16B chunks (64 rows x 64 cols)
    #pragma unroll
    for (int i = 0; i < 2; ++i) {
        int flat = tid + i * 256;
        int r = flat >> 3, c = flat & 7;
        int gr = row0 + r;
        if (gr < n) {
            uint4 v = *(const uint4*)(xl + r * XSTR + c * 8);
            *(uint4*)(hpb + (size_t)gr * OUT_CH + c * 8) = v;
        }
    }
}

// ---------------- 8: aggregate — 2 edges/wave via half-waves ----------------
__global__ __launch_bounds__(256) void aggregate_kernel(
    const int* __restrict__ row_start, const int* __restrict__ csr_row,
    const unsigned short* __restrict__ hpb, const float* __restrict__ dinv,
    const float* __restrict__ bias, float* __restrict__ out, int n)
{
    int wid  = (blockIdx.x * 256 + threadIdx.x) >> 6;   // node id
    int lane = threadIdx.x & 63;
    if (wid >= n) return;
    int half = lane >> 5;      // which edge of the pair
    int hl   = lane & 31;      // channel-pair index

    const unsigned int* hp32 = (const unsigned int*)hpb;   // row stride 32 uints

    int s0 = row_start[wid];
    int s1 = row_start[wid + 1];

    float a0l=0.f,a0h=0.f,a1l=0.f,a1h=0.f,a2l=0.f,a2h=0.f,a3l=0.f,a3h=0.f;

    for (int base = s0; base < s1; base += 64) {
        int cnt  = min(64, s1 - base);
        int ridx = (base + lane < s1) ? csr_row[base + lane] : 0;
        int j = 0;
        for (; j + 8 <= cnt; j += 8) {      // 8 edges: 4 per half-wave
            int r0 = __shfl(ridx, j     + half);
            int r1 = __shfl(ridx, j + 2 + half);
            int r2 = __shfl(ridx, j + 4 + half);
            int r3 = __shfl(ridx, j + 6 + half);
            unsigned int v0 = hp32[(size_t)r0 * 32 + hl];
            unsigned int v1 = hp32[(size_t)r1 * 32 + hl];
            unsigned int v2 = hp32[(size_t)r2 * 32 + hl];
            unsigned int v3 = hp32[(size_t)r3 * 32 + hl];
            a0l += __uint_as_float(v0 << 16); a0h += __uint_as_float(v0 & 0xFFFF0000u);
            a1l += __uint_as_float(v1 << 16); a1h += __uint_as_float(v1 & 0xFFFF0000u);
            a2l += __uint_as_float(v2 << 16); a2h += __uint_as_float(v2 & 0xFFFF0000u);
            a3l += __uint_as_float(v3 << 16); a3h += __uint_as_float(v3 & 0xFFFF0000u);
        }
        for (; j < cnt; j += 2) {           // tail: up to 2 edges at a time
            int e = j + half;
            int r = __shfl(ridx, e);
            unsigned int v = (e < cnt) ? hp32[(size_t)r * 32 + hl] : 0u;
            a0l += __uint_as_float(v << 16); a0h += __uint_as_float(v & 0xFFFF0000u);
        }
    }
    float sl = ((a0l + a1l) + (a2l + a3l));
    float sh = ((a0h + a1h) + (a2h + a3h));
    sl += __shfl_xor(sl, 32);
    sh += __shfl_xor(sh, 32);

    if (half == 0) {
        unsigned int sv = hp32[(size_t)wid * 32 + hl];   // self loop
        sl += __uint_as_float(sv << 16);
        sh += __uint_as_float(sv & 0xFFFF0000u);
        float d = dinv[wid];
        float2 bb = ((const float2*)bias)[hl];
        float2 o;
        o.x = fmaf(d, sl, bb.x);
        o.y = fmaf(d, sh, bb.y);
        ((float2*)(out + (size_t)wid * OUT_CH))[hl] = o;
    }
}

extern "C" void kernel_launch(void* const* d_in, const int* in_sizes, int n_in,
                              void* d_out, int out_size, void* d_ws, size_t ws_size,
                              hipStream_t stream) {
    const float* x  = (const float*)d_in[0];
    const int*   ei = (const int*)d_in[1];
    const float* W  = (const float*)d_in[2];
    const float* b  = (const float*)d_in[3];
    float*       out = (float*)d_out;

    int n = in_sizes[0] / IN_CH;     // 100000
    int E = in_sizes[1] / 2;         // 1600000
    const int* row = ei;
    const int* col = ei + E;

    int NB   = (n + BNODES - 1) >> BSHIFT;           // 782
    int NBLK = (E + CH_EDGES - 1) / CH_EDGES;        // 224
    int TOT  = NB * NBLK;                            // 175168
    int nbs  = (TOT + 255) / 256;                    // 685 (<=1024)

    // workspace layout; hpb (bf16, n*64) overlays pairs (dead after bucket_sort)
    char* ws = (char*)d_ws;
    int*   blkcnt       = (int*)ws;   ws += (size_t)TOT * 4;
    int*   blkoff       = (int*)ws;   ws += (size_t)TOT * 4;
    int*   partial      = (int*)ws;   ws += 1024 * 4;
    int*   bucket_start = (int*)ws;   ws += (size_t)(NB + 1) * 4;
    int*   row_start    = (int*)ws;   ws += (size_t)(n + 1) * 4;
    float* dinv         = (float*)ws; ws += (size_t)n * 4;
    int*   csr_row      = (int*)ws;   ws += (size_t)E * 4;
    unsigned short* wbt = (unsigned short*)ws; ws += (size_t)IN_CH * OUT_CH * 2;
    ws = (char*)(((uintptr_t)ws + 255) & ~(uintptr_t)255);
    int*            pairs = (int*)ws;              // E ints        (phase 1)
    unsigned short* hpb   = (unsigned short*)ws;   // n*64 bf16     (phase 2)

    wprep_kernel      <<<(IN_CH * OUT_CH) / 256, 256, 0, stream>>>(W, wbt);
    count_kernel      <<<NBLK, 1024, 0, stream>>>(col, blkcnt, E, NBLK, NB);
    scan1_kernel      <<<nbs, 256, 0, stream>>>(blkcnt, partial, TOT);
    scan2_kernel      <<<1, 1024, 0, stream>>>(partial, nbs);
    scan3_kernel      <<<nbs, 256, 0, stream>>>(blkcnt, partial, blkoff, bucket_start,
                                                TOT, NBLK, NB, E);
    place_kernel      <<<NBLK, 1024, 0, stream>>>(row, col, blkoff, pairs, E, NBLK, NB);
    bucket_sort_kernel<<<NB, 256, 0, stream>>>(bucket_start, pairs, csr_row, row_start, dinv, n, E);
    gemm_kernel       <<<(n + 63) / 64, 256, 0, stream>>>(x, wbt, dinv, hpb, n);
    aggregate_kernel  <<<(n + 3) / 4, 256, 0, stream>>>(row_start, csr_row, hpb, dinv, b, out, n);
}